// Round 19
// baseline (41.448 us; speedup 1.0000x reference)
//
#include <hip/hip_runtime.h>

// LePE window attention, 32x32x16 bf16 MFMA, reg-P via v_permlane32_swap_b32.
// R19 = R17 resubmitted verbatim again (rounds 17 AND 18 both died with the
// same dead-pod "connection closed while sending first message" error before
// the kernel was ever sent; rounds 2/3 showed the same pattern and round 4
// got a fresh container). 2-phase staging split: A-half = tokens [0,256),
// B-half = [256,512). Prologue issues ALL global loads (B pinned via empty
// asm so the compiler cannot sink the loads); write A, barrier, compute
// kt 0-7 (reads only tokens <256), write B (loads long landed), barrier,
// compute kt 8-15.
// Body per kt = R14 (no setprio, ones-MFMA lsum, cvt_pk, b128 frags).
// Structure: 256 blocks x 1024 threads (16 waves), 1 block/CU.
// LDS = K[512][40] + V^T[32][536] bf16 = 73.5 KB.

namespace {
constexpr int Bn   = 8;
constexpr int Ww   = 64;
constexpr int Cc   = 128;
constexpr int HD   = 32;
constexpr int WSP  = 8;
constexpr int NTOK = 512;
constexpr int LL   = 64 * 64;
// 32^-0.5 * log2(e): exp(s) == exp2(s') with scale folded into Q
constexpr float SCALE_L2E = 0.17677669529663687f * 1.4426950408889634f;
constexpr int KPAD = 40;   // K row stride in shorts (80B rows -> 16B-aligned frags)
constexpr int VPAD = 536;  // V^T row stride in shorts (1072B rows -> 16B-aligned)
}

typedef __bf16 bf16x8 __attribute__((ext_vector_type(8)));
typedef float  f32x16 __attribute__((ext_vector_type(16)));
typedef float  fx4    __attribute__((ext_vector_type(4)));
typedef unsigned int uint32x4 __attribute__((ext_vector_type(4)));

// dst.lo = bf16(x), dst.hi = bf16(y) — single VALU op (RNE)
__device__ inline unsigned cvtpk(float x, float y) {
    unsigned r;
    asm("v_cvt_pk_bf16_f32 %0, %1, %2" : "=v"(r) : "v"(x), "v"(y));
    return r;
}

__global__ __launch_bounds__(1024, 4) void attn_kernel(const float* __restrict__ qkv,
                                                       const float* __restrict__ cw,
                                                       const float* __restrict__ cb,
                                                       float* __restrict__ out) {
    const int blk = blockIdx.x;          // 0..255
    const int w   = blk >> 2;            // window 0..63
    const int h   = blk & 3;             // head
    const int b   = w >> 3;
    const int wb  = w & 7;
    const int tid = threadIdx.x;         // 0..1023
    const int wv  = tid >> 6;            // wave 0..15 -> 32 q rows each
    const int lane = tid & 63;
    const int l31 = lane & 31;
    const int h5  = lane >> 5;

    const float* qp = qkv;
    const float* kp = qkv + (size_t)Bn * LL * Cc;
    const float* vp = qkv + (size_t)2 * Bn * LL * Cc;

    __shared__ short K_lds[NTOK][KPAD];
    __shared__ short VT_lds[HD][VPAD];

    // ---- staging geometry: A item = tid (tokens [0,256)), B = tid+1024 ----
    const int ja  = tid & 7;             // d-group (same for A and B: 1024 % 8 == 0)
    const int t0a = (tid >> 3) * 2;              // 0..254
    const int t0b = ((tid + 1024) >> 3) * 2;     // 256..510
    const int lqa = (t0a >> 3) * Ww + wb * WSP + (t0a & 7);
    const int lqb = (t0b >> 3) * Ww + wb * WSP + (t0b & 7);
    const size_t ga = ((size_t)b * LL + lqa) * Cc + h * HD + ja * 4;
    const size_t gb = ((size_t)b * LL + lqb) * Cc + h * HD + ja * 4;

    // ---- issue ALL global loads first (T14) ----
    const float4 kA0 = *reinterpret_cast<const float4*>(kp + ga);
    const float4 kA1 = *reinterpret_cast<const float4*>(kp + ga + Cc);
    const float4 vA0 = *reinterpret_cast<const float4*>(vp + ga);
    const float4 vA1 = *reinterpret_cast<const float4*>(vp + ga + Cc);
    fx4 kB0 = *reinterpret_cast<const fx4*>(kp + gb);
    fx4 kB1 = *reinterpret_cast<const fx4*>(kp + gb + Cc);
    fx4 vB0 = *reinterpret_cast<const fx4*>(vp + gb);
    fx4 vB1 = *reinterpret_cast<const fx4*>(vp + gb + Cc);
    // pin B in registers: compiler must not sink these loads into phase gap
    asm volatile("" : "+v"(kB0), "+v"(kB1), "+v"(vB0), "+v"(vB1));

    const int qtok = wv * 32 + l31;      // q tok; d = dc*16 + h5*8 + e
    const int qlqi = (qtok >> 3) * Ww + wb * WSP + (qtok & 7);
    const float* qptr = qp + ((size_t)b * LL + qlqi) * Cc + h * HD + h5 * 8;
    const float4 qa0 = *reinterpret_cast<const float4*>(qptr);
    const float4 qc0 = *reinterpret_cast<const float4*>(qptr + 4);
    const float4 qa1 = *reinterpret_cast<const float4*>(qptr + 16);
    const float4 qc1 = *reinterpret_cast<const float4*>(qptr + 20);

    // ---- write A half ----
    {
        uint2 pk0, pk1;
        pk0.x = cvtpk(kA0.x, kA0.y);  pk0.y = cvtpk(kA0.z, kA0.w);
        pk1.x = cvtpk(kA1.x, kA1.y);  pk1.y = cvtpk(kA1.z, kA1.w);
        *reinterpret_cast<uint2*>(&K_lds[t0a][ja * 4]) = pk0;
        *reinterpret_cast<uint2*>(&K_lds[t0a + 1][ja * 4]) = pk1;
        *reinterpret_cast<unsigned*>(&VT_lds[ja * 4 + 0][t0a]) = cvtpk(vA0.x, vA1.x);
        *reinterpret_cast<unsigned*>(&VT_lds[ja * 4 + 1][t0a]) = cvtpk(vA0.y, vA1.y);
        *reinterpret_cast<unsigned*>(&VT_lds[ja * 4 + 2][t0a]) = cvtpk(vA0.z, vA1.z);
        *reinterpret_cast<unsigned*>(&VT_lds[ja * 4 + 3][t0a]) = cvtpk(vA0.w, vA1.w);
    }

    // ---- Q fragments ----
    bf16x8 qf[2];
    {
        uint32x4 u;
        u.x = cvtpk(qa0.x * SCALE_L2E, qa0.y * SCALE_L2E);
        u.y = cvtpk(qa0.z * SCALE_L2E, qa0.w * SCALE_L2E);
        u.z = cvtpk(qc0.x * SCALE_L2E, qc0.y * SCALE_L2E);
        u.w = cvtpk(qc0.z * SCALE_L2E, qc0.w * SCALE_L2E);
        qf[0] = __builtin_bit_cast(bf16x8, u);
        u.x = cvtpk(qa1.x * SCALE_L2E, qa1.y * SCALE_L2E);
        u.y = cvtpk(qa1.z * SCALE_L2E, qa1.w * SCALE_L2E);
        u.z = cvtpk(qc1.x * SCALE_L2E, qc1.y * SCALE_L2E);
        u.w = cvtpk(qc1.z * SCALE_L2E, qc1.w * SCALE_L2E);
        qf[1] = __builtin_bit_cast(bf16x8, u);
    }
    __syncthreads();   // barrier 1: A half ready

    f32x16 acc  = (f32x16)(0.f);
    f32x16 lacc = (f32x16)(0.f);         // row-sum accumulator (ones-MFMA)
    const f32x16 z16 = (f32x16)(0.f);

    uint32x4 onesu;
    onesu.x = 0x3F803F80u; onesu.y = 0x3F803F80u;
    onesu.z = 0x3F803F80u; onesu.w = 0x3F803F80u;
    const bf16x8 onesf = __builtin_bit_cast(bf16x8, onesu);

    auto load_kf = [&](int kt, bf16x8* kf) {
        const int krow = kt * 32 + l31;
#pragma unroll
        for (int dc = 0; dc < 2; ++dc)
            kf[dc] = __builtin_bit_cast(bf16x8,
                *reinterpret_cast<const uint32x4*>(&K_lds[krow][dc * 16 + h5 * 8]));
    };
    auto load_vu = [&](int kt, uint32x4* vu) {
#pragma unroll
        for (int kw = 0; kw < 2; ++kw) {
            const int kcol = kt * 32 + kw * 16 + h5 * 8;
            vu[kw] = *reinterpret_cast<const uint32x4*>(&VT_lds[l31][kcol]);
        }
    };
    auto softmax_pv = [&](const f32x16& s, const uint32x4* vu) {
        float pe[16];
#pragma unroll
        for (int i = 0; i < 16; ++i) pe[i] = __builtin_amdgcn_exp2f(s[i]);
        unsigned dw[8];
#pragma unroll
        for (int i = 0; i < 8; ++i) dw[i] = cvtpk(pe[2 * i], pe[2 * i + 1]);
#pragma unroll
        for (int kw = 0; kw < 2; ++kw) {
            unsigned a0 = dw[4 * kw + 0], b0 = dw[4 * kw + 2];
            unsigned a1 = dw[4 * kw + 1], b1 = dw[4 * kw + 3];
            asm("v_permlane32_swap_b32 %0, %1" : "+v"(a0), "+v"(b0));
            asm("v_permlane32_swap_b32 %0, %1" : "+v"(a1), "+v"(b1));
            uint32x4 pu; pu.x = a0; pu.y = a1; pu.z = b0; pu.w = b1;
            const bf16x8 pf = __builtin_bit_cast(bf16x8, pu);
            acc  = __builtin_amdgcn_mfma_f32_32x32x16_bf16(
                pf, __builtin_bit_cast(bf16x8, vu[kw]), acc, 0, 0, 0);
            lacc = __builtin_amdgcn_mfma_f32_32x32x16_bf16(
                pf, onesf, lacc, 0, 0, 0);
        }
    };
    // one phase = 8 kt tiles within [base, base+8); prefetch wraps in-phase
    auto phase = [&](int base) {
        bf16x8 kf[2];
        load_kf(base, kf);
        for (int kt = base; kt < base + 8; ++kt) {
            f32x16 s = z16;
            s = __builtin_amdgcn_mfma_f32_32x32x16_bf16(kf[0], qf[0], s, 0, 0, 0);
            s = __builtin_amdgcn_mfma_f32_32x32x16_bf16(kf[1], qf[1], s, 0, 0, 0);
            // lane holds S^T[k][q=l31], k = (reg&3) + 8*(reg>>2) + 4*h5 + kt*32
            bf16x8 kfn[2];
            load_kf(base + ((kt + 1 - base) & 7), kfn);
            uint32x4 vu[2];
            load_vu(kt, vu);
            softmax_pv(s, vu);
            kf[0] = kfn[0];
            kf[1] = kfn[1];
        }
    };

    phase(0);          // reads only tokens [0,256)

    // ---- write B half (loads landed during phase 1) ----
    {
        uint2 pk0, pk1;
        pk0.x = cvtpk(kB0[0], kB0[1]);  pk0.y = cvtpk(kB0[2], kB0[3]);
        pk1.x = cvtpk(kB1[0], kB1[1]);  pk1.y = cvtpk(kB1[2], kB1[3]);
        *reinterpret_cast<uint2*>(&K_lds[t0b][ja * 4]) = pk0;
        *reinterpret_cast<uint2*>(&K_lds[t0b + 1][ja * 4]) = pk1;
        *reinterpret_cast<unsigned*>(&VT_lds[ja * 4 + 0][t0b]) = cvtpk(vB0[0], vB1[0]);
        *reinterpret_cast<unsigned*>(&VT_lds[ja * 4 + 1][t0b]) = cvtpk(vB0[1], vB1[1]);
        *reinterpret_cast<unsigned*>(&VT_lds[ja * 4 + 2][t0b]) = cvtpk(vB0[2], vB1[2]);
        *reinterpret_cast<unsigned*>(&VT_lds[ja * 4 + 3][t0b]) = cvtpk(vB0[3], vB1[3]);
    }
    __syncthreads();   // barrier 2: B half ready

    phase(8);          // reads only tokens [256,512)

    // ---- LePE conv: lane owns channel d = l31 of head h ----
    const int ch = h * HD + l31;
    float wreg[9];
#pragma unroll
    for (int wi = 0; wi < 9; ++wi) wreg[wi] = cw[ch * 9 + wi];
    const float bias = cb[ch];

    const int tok0 = wv * 32;
    // Packed V halo: 52 bf16 toks [tok0 + 4*h5 - 12, +40) as 26 uints.
    // Needed tap range rel. tok0+4h5 is [-9,+36]; clamped chunk slots are only
    // tokens <0 / >=512, all rowok-guarded below.
    unsigned hw[26];
    {
        const int segbase = tok0 + 4 * h5 - 12;
#pragma unroll
        for (int c2 = 0; c2 < 13; ++c2) {
            int t = segbase + 4 * c2;
            t = t < 0 ? 0 : (t > NTOK - 4 ? NTOK - 4 : t);
            const uint2 u = *reinterpret_cast<const uint2*>(&VT_lds[l31][t]);
            hw[c2 * 2 + 0] = u.x;
            hw[c2 * 2 + 1] = u.y;
        }
    }

    // ---- epilogue: normalize (in-lane rcp of lacc) + conv + store ----
#pragma unroll
    for (int r = 0; r < 16; ++r) {
        const int c_r = (r & 3) + 8 * (r >> 2);           // q row offset (compile-time)
        const float iv = __builtin_amdgcn_rcpf(lacc[r]);  // 1/lsum for q_r, in-lane
        const int tok = tok0 + c_r + 4 * h5;
        float cv = bias;
#pragma unroll
        for (int dy = -1; dy <= 1; ++dy) {
            const bool rowok = (unsigned)(tok + dy * 8) < (unsigned)NTOK;
#pragma unroll
            for (int dx = -1; dx <= 1; ++dx) {
                const int idx = c_r + 12 + dy * 8 + dx;   // compile-time, in [3,48]
                const unsigned word = hw[idx >> 1];
                const float tap = __builtin_bit_cast(float,
                    (idx & 1) ? (word & 0xFFFF0000u) : (word << 16));
                bool ok = rowok;
                if (dx == -1) ok = ok && (((r & 3) != 0) || (h5 != 0));  // wc > 0
                if (dx == +1) ok = ok && (((r & 3) != 3) || (h5 == 0));  // wc < 7
                cv += ok ? wreg[(dy + 1) * 3 + (dx + 1)] * tap : 0.f;
            }
        }
        const int lqi = (tok >> 3) * Ww + wb * WSP + (tok & 7);
        out[((size_t)b * LL + lqi) * Cc + ch] = acc[r] * iv + cv;
    }
}

extern "C" void kernel_launch(void* const* d_in, const int* in_sizes, int n_in,
                              void* d_out, int out_size, void* d_ws, size_t ws_size,
                              hipStream_t stream) {
    const float* qkv = (const float*)d_in[0];
    const float* cw  = (const float*)d_in[1];
    const float* cb  = (const float*)d_in[2];
    float* out = (float*)d_out;

    attn_kernel<<<256, 1024, 0, stream>>>(qkv, cw, cb, out);
}

// Round 20
// 38.558 us; speedup vs baseline: 1.0750x; 1.0750x over previous
//
#include <hip/hip_runtime.h>

// LePE window attention, 32x32x16 bf16 MFMA, reg-P via v_permlane32_swap_b32.
// R20: R17's 2-phase staging split with two spill-killers (R19 spilled:
// VGPR=64 + 61 MB scratch writes, invalidating the overlap experiment):
//   1) __launch_bounds__(1024, 2) -> 256-VGPR allocator budget (LDS already
//      limits us to 1 block/CU = 16 waves, so nothing is lost);
//   2) B-half pinned as 16 SCALAR floats (R19's "+v" on ext-vector fx4
//      operands is the suspected quad-alloc spill trigger).
// A-half = tokens [0,256) staged in prologue; compute kt 0-7; write B-half
// (loads issued in prologue, landed during phase 1); barrier; compute kt 8-15.
// Body per kt = R14 (no setprio, ones-MFMA lsum, cvt_pk, b128 frags).
// Structure: 256 blocks x 1024 threads (16 waves), 1 block/CU.
// LDS = K[512][40] + V^T[32][536] bf16 = 73.5 KB.

namespace {
constexpr int Bn   = 8;
constexpr int Ww   = 64;
constexpr int Cc   = 128;
constexpr int HD   = 32;
constexpr int WSP  = 8;
constexpr int NTOK = 512;
constexpr int LL   = 64 * 64;
// 32^-0.5 * log2(e): exp(s) == exp2(s') with scale folded into Q
constexpr float SCALE_L2E = 0.17677669529663687f * 1.4426950408889634f;
constexpr int KPAD = 40;   // K row stride in shorts (80B rows -> 16B-aligned frags)
constexpr int VPAD = 536;  // V^T row stride in shorts (1072B rows -> 16B-aligned)
}

typedef __bf16 bf16x8 __attribute__((ext_vector_type(8)));
typedef float  f32x16 __attribute__((ext_vector_type(16)));
typedef unsigned int uint32x4 __attribute__((ext_vector_type(4)));

// dst.lo = bf16(x), dst.hi = bf16(y) — single VALU op (RNE)
__device__ inline unsigned cvtpk(float x, float y) {
    unsigned r;
    asm("v_cvt_pk_bf16_f32 %0, %1, %2" : "=v"(r) : "v"(x), "v"(y));
    return r;
}

__global__ __launch_bounds__(1024, 2) void attn_kernel(const float* __restrict__ qkv,
                                                       const float* __restrict__ cw,
                                                       const float* __restrict__ cb,
                                                       float* __restrict__ out) {
    const int blk = blockIdx.x;          // 0..255
    const int w   = blk >> 2;            // window 0..63
    const int h   = blk & 3;             // head
    const int b   = w >> 3;
    const int wb  = w & 7;
    const int tid = threadIdx.x;         // 0..1023
    const int wv  = tid >> 6;            // wave 0..15 -> 32 q rows each
    const int lane = tid & 63;
    const int l31 = lane & 31;
    const int h5  = lane >> 5;

    const float* qp = qkv;
    const float* kp = qkv + (size_t)Bn * LL * Cc;
    const float* vp = qkv + (size_t)2 * Bn * LL * Cc;

    __shared__ short K_lds[NTOK][KPAD];
    __shared__ short VT_lds[HD][VPAD];

    // ---- staging geometry: A item = tid (tokens [0,256)), B = tid+1024 ----
    const int ja  = tid & 7;             // d-group (same for A and B: 1024 % 8 == 0)
    const int t0a = (tid >> 3) * 2;              // 0..254
    const int t0b = ((tid + 1024) >> 3) * 2;     // 256..510
    const int lqa = (t0a >> 3) * Ww + wb * WSP + (t0a & 7);
    const int lqb = (t0b >> 3) * Ww + wb * WSP + (t0b & 7);
    const size_t ga = ((size_t)b * LL + lqa) * Cc + h * HD + ja * 4;
    const size_t gb = ((size_t)b * LL + lqb) * Cc + h * HD + ja * 4;

    // ---- issue ALL global loads in prologue (T14) ----
    const float4 kA0 = *reinterpret_cast<const float4*>(kp + ga);
    const float4 kA1 = *reinterpret_cast<const float4*>(kp + ga + Cc);
    const float4 vA0 = *reinterpret_cast<const float4*>(vp + ga);
    const float4 vA1 = *reinterpret_cast<const float4*>(vp + ga + Cc);

    const int qtok = wv * 32 + l31;      // q tok; d = dc*16 + h5*8 + e
    const int qlqi = (qtok >> 3) * Ww + wb * WSP + (qtok & 7);
    const float* qptr = qp + ((size_t)b * LL + qlqi) * Cc + h * HD + h5 * 8;
    const float4 qa0 = *reinterpret_cast<const float4*>(qptr);
    const float4 qc0 = *reinterpret_cast<const float4*>(qptr + 4);
    const float4 qa1 = *reinterpret_cast<const float4*>(qptr + 16);
    const float4 qc1 = *reinterpret_cast<const float4*>(qptr + 20);

    // B-half loads last (consumed last), pinned as 16 scalar floats
    const float4 tkB0 = *reinterpret_cast<const float4*>(kp + gb);
    const float4 tkB1 = *reinterpret_cast<const float4*>(kp + gb + Cc);
    const float4 tvB0 = *reinterpret_cast<const float4*>(vp + gb);
    const float4 tvB1 = *reinterpret_cast<const float4*>(vp + gb + Cc);
    float b00 = tkB0.x, b01 = tkB0.y, b02 = tkB0.z, b03 = tkB0.w;
    float b04 = tkB1.x, b05 = tkB1.y, b06 = tkB1.z, b07 = tkB1.w;
    float b08 = tvB0.x, b09 = tvB0.y, b10 = tvB0.z, b11 = tvB0.w;
    float b12 = tvB1.x, b13 = tvB1.y, b14 = tvB1.z, b15 = tvB1.w;
    asm volatile("" : "+v"(b00), "+v"(b01), "+v"(b02), "+v"(b03),
                      "+v"(b04), "+v"(b05), "+v"(b06), "+v"(b07),
                      "+v"(b08), "+v"(b09), "+v"(b10), "+v"(b11),
                      "+v"(b12), "+v"(b13), "+v"(b14), "+v"(b15));

    // ---- write A half ----
    {
        uint2 pk0, pk1;
        pk0.x = cvtpk(kA0.x, kA0.y);  pk0.y = cvtpk(kA0.z, kA0.w);
        pk1.x = cvtpk(kA1.x, kA1.y);  pk1.y = cvtpk(kA1.z, kA1.w);
        *reinterpret_cast<uint2*>(&K_lds[t0a][ja * 4]) = pk0;
        *reinterpret_cast<uint2*>(&K_lds[t0a + 1][ja * 4]) = pk1;
        *reinterpret_cast<unsigned*>(&VT_lds[ja * 4 + 0][t0a]) = cvtpk(vA0.x, vA1.x);
        *reinterpret_cast<unsigned*>(&VT_lds[ja * 4 + 1][t0a]) = cvtpk(vA0.y, vA1.y);
        *reinterpret_cast<unsigned*>(&VT_lds[ja * 4 + 2][t0a]) = cvtpk(vA0.z, vA1.z);
        *reinterpret_cast<unsigned*>(&VT_lds[ja * 4 + 3][t0a]) = cvtpk(vA0.w, vA1.w);
    }

    // ---- Q fragments ----
    bf16x8 qf[2];
    {
        uint32x4 u;
        u.x = cvtpk(qa0.x * SCALE_L2E, qa0.y * SCALE_L2E);
        u.y = cvtpk(qa0.z * SCALE_L2E, qa0.w * SCALE_L2E);
        u.z = cvtpk(qc0.x * SCALE_L2E, qc0.y * SCALE_L2E);
        u.w = cvtpk(qc0.z * SCALE_L2E, qc0.w * SCALE_L2E);
        qf[0] = __builtin_bit_cast(bf16x8, u);
        u.x = cvtpk(qa1.x * SCALE_L2E, qa1.y * SCALE_L2E);
        u.y = cvtpk(qa1.z * SCALE_L2E, qa1.w * SCALE_L2E);
        u.z = cvtpk(qc1.x * SCALE_L2E, qc1.y * SCALE_L2E);
        u.w = cvtpk(qc1.z * SCALE_L2E, qc1.w * SCALE_L2E);
        qf[1] = __builtin_bit_cast(bf16x8, u);
    }
    __syncthreads();   // barrier 1: A half ready

    f32x16 acc  = (f32x16)(0.f);
    f32x16 lacc = (f32x16)(0.f);         // row-sum accumulator (ones-MFMA)
    const f32x16 z16 = (f32x16)(0.f);

    uint32x4 onesu;
    onesu.x = 0x3F803F80u; onesu.y = 0x3F803F80u;
    onesu.z = 0x3F803F80u; onesu.w = 0x3F803F80u;
    const bf16x8 onesf = __builtin_bit_cast(bf16x8, onesu);

    auto load_kf = [&](int kt, bf16x8* kf) {
        const int krow = kt * 32 + l31;
#pragma unroll
        for (int dc = 0; dc < 2; ++dc)
            kf[dc] = __builtin_bit_cast(bf16x8,
                *reinterpret_cast<const uint32x4*>(&K_lds[krow][dc * 16 + h5 * 8]));
    };
    auto load_vu = [&](int kt, uint32x4* vu) {
#pragma unroll
        for (int kw = 0; kw < 2; ++kw) {
            const int kcol = kt * 32 + kw * 16 + h5 * 8;
            vu[kw] = *reinterpret_cast<const uint32x4*>(&VT_lds[l31][kcol]);
        }
    };
    auto softmax_pv = [&](const f32x16& s, const uint32x4* vu) {
        float pe[16];
#pragma unroll
        for (int i = 0; i < 16; ++i) pe[i] = __builtin_amdgcn_exp2f(s[i]);
        unsigned dw[8];
#pragma unroll
        for (int i = 0; i < 8; ++i) dw[i] = cvtpk(pe[2 * i], pe[2 * i + 1]);
#pragma unroll
        for (int kw = 0; kw < 2; ++kw) {
            unsigned a0 = dw[4 * kw + 0], b0 = dw[4 * kw + 2];
            unsigned a1 = dw[4 * kw + 1], b1 = dw[4 * kw + 3];
            asm("v_permlane32_swap_b32 %0, %1" : "+v"(a0), "+v"(b0));
            asm("v_permlane32_swap_b32 %0, %1" : "+v"(a1), "+v"(b1));
            uint32x4 pu; pu.x = a0; pu.y = a1; pu.z = b0; pu.w = b1;
            const bf16x8 pf = __builtin_bit_cast(bf16x8, pu);
            acc  = __builtin_amdgcn_mfma_f32_32x32x16_bf16(
                pf, __builtin_bit_cast(bf16x8, vu[kw]), acc, 0, 0, 0);
            lacc = __builtin_amdgcn_mfma_f32_32x32x16_bf16(
                pf, onesf, lacc, 0, 0, 0);
        }
    };
    // one phase = 8 kt tiles within [base, base+8); prefetch wraps in-phase
    auto phase = [&](int base) {
        bf16x8 kf[2];
        load_kf(base, kf);
        for (int kt = base; kt < base + 8; ++kt) {
            f32x16 s = z16;
            s = __builtin_amdgcn_mfma_f32_32x32x16_bf16(kf[0], qf[0], s, 0, 0, 0);
            s = __builtin_amdgcn_mfma_f32_32x32x16_bf16(kf[1], qf[1], s, 0, 0, 0);
            // lane holds S^T[k][q=l31], k = (reg&3) + 8*(reg>>2) + 4*h5 + kt*32
            bf16x8 kfn[2];
            load_kf(base + ((kt + 1 - base) & 7), kfn);
            uint32x4 vu[2];
            load_vu(kt, vu);
            softmax_pv(s, vu);
            kf[0] = kfn[0];
            kf[1] = kfn[1];
        }
    };

    phase(0);          // reads only tokens [0,256)

    // ---- write B half (loads landed during phase 1) ----
    {
        uint2 pk0, pk1;
        pk0.x = cvtpk(b00, b01);  pk0.y = cvtpk(b02, b03);
        pk1.x = cvtpk(b04, b05);  pk1.y = cvtpk(b06, b07);
        *reinterpret_cast<uint2*>(&K_lds[t0b][ja * 4]) = pk0;
        *reinterpret_cast<uint2*>(&K_lds[t0b + 1][ja * 4]) = pk1;
        *reinterpret_cast<unsigned*>(&VT_lds[ja * 4 + 0][t0b]) = cvtpk(b08, b12);
        *reinterpret_cast<unsigned*>(&VT_lds[ja * 4 + 1][t0b]) = cvtpk(b09, b13);
        *reinterpret_cast<unsigned*>(&VT_lds[ja * 4 + 2][t0b]) = cvtpk(b10, b14);
        *reinterpret_cast<unsigned*>(&VT_lds[ja * 4 + 3][t0b]) = cvtpk(b11, b15);
    }
    __syncthreads();   // barrier 2: B half ready

    phase(8);          // reads only tokens [256,512)

    // ---- LePE conv: lane owns channel d = l31 of head h ----
    const int ch = h * HD + l31;
    float wreg[9];
#pragma unroll
    for (int wi = 0; wi < 9; ++wi) wreg[wi] = cw[ch * 9 + wi];
    const float bias = cb[ch];

    const int tok0 = wv * 32;
    // Packed V halo: 52 bf16 toks [tok0 + 4*h5 - 12, +40) as 26 uints.
    // Needed tap range rel. tok0+4h5 is [-9,+36]; clamped chunk slots are only
    // tokens <0 / >=512, all rowok-guarded below.
    unsigned hw[26];
    {
        const int segbase = tok0 + 4 * h5 - 12;
#pragma unroll
        for (int c2 = 0; c2 < 13; ++c2) {
            int t = segbase + 4 * c2;
            t = t < 0 ? 0 : (t > NTOK - 4 ? NTOK - 4 : t);
            const uint2 u = *reinterpret_cast<const uint2*>(&VT_lds[l31][t]);
            hw[c2 * 2 + 0] = u.x;
            hw[c2 * 2 + 1] = u.y;
        }
    }

    // ---- epilogue: normalize (in-lane rcp of lacc) + conv + store ----
#pragma unroll
    for (int r = 0; r < 16; ++r) {
        const int c_r = (r & 3) + 8 * (r >> 2);           // q row offset (compile-time)
        const float iv = __builtin_amdgcn_rcpf(lacc[r]);  // 1/lsum for q_r, in-lane
        const int tok = tok0 + c_r + 4 * h5;
        float cv = bias;
#pragma unroll
        for (int dy = -1; dy <= 1; ++dy) {
            const bool rowok = (unsigned)(tok + dy * 8) < (unsigned)NTOK;
#pragma unroll
            for (int dx = -1; dx <= 1; ++dx) {
                const int idx = c_r + 12 + dy * 8 + dx;   // compile-time, in [3,48]
                const unsigned word = hw[idx >> 1];
                const float tap = __builtin_bit_cast(float,
                    (idx & 1) ? (word & 0xFFFF0000u) : (word << 16));
                bool ok = rowok;
                if (dx == -1) ok = ok && (((r & 3) != 0) || (h5 != 0));  // wc > 0
                if (dx == +1) ok = ok && (((r & 3) != 3) || (h5 == 0));  // wc < 7
                cv += ok ? wreg[(dy + 1) * 3 + (dx + 1)] * tap : 0.f;
            }
        }
        const int lqi = (tok >> 3) * Ww + wb * WSP + (tok & 7);
        out[((size_t)b * LL + lqi) * Cc + ch] = acc[r] * iv + cv;
    }
}

extern "C" void kernel_launch(void* const* d_in, const int* in_sizes, int n_in,
                              void* d_out, int out_size, void* d_ws, size_t ws_size,
                              hipStream_t stream) {
    const float* qkv = (const float*)d_in[0];
    const float* cw  = (const float*)d_in[1];
    const float* cb  = (const float*)d_in[2];
    float* out = (float*)d_out;

    attn_kernel<<<256, 1024, 0, stream>>>(qkv, cw, cb, out);
}

// Round 21
// 32.131 us; speedup vs baseline: 1.2899x; 1.2000x over previous
//
#include <hip/hip_runtime.h>

// LePE window attention, 32x32x16 bf16 MFMA, reg-P via v_permlane32_swap_b32.
// R21: q-tile pairing — 8 waves x 64 q rows (two 32-row q-tiles per wave).
// One kf/vu LDS read now feeds TWO q-tiles' MFMAs: per-CU DS-read issue
// halves (~5.1 -> ~2.6 us), and the two independent per-qt chains give
// intra-wave ILP (qt1 QK-MFMAs issue under qt0's exp chain). Costs TLP
// (2 waves/SIMD). Phase-split staging permanently abandoned (R12/R19/R20:
// allocator spills any cross-phase register hold). Body = R14 otherwise.
// Structure: 256 blocks x 512 threads (8 waves), staging once per block.
// LDS = K[512][40] + V^T[32][536] bf16 = 73.5 KB.

namespace {
constexpr int Bn   = 8;
constexpr int Ww   = 64;
constexpr int Cc   = 128;
constexpr int HD   = 32;
constexpr int WSP  = 8;
constexpr int NTOK = 512;
constexpr int LL   = 64 * 64;
// 32^-0.5 * log2(e): exp(s) == exp2(s') with scale folded into Q
constexpr float SCALE_L2E = 0.17677669529663687f * 1.4426950408889634f;
constexpr int KPAD = 40;   // K row stride in shorts (80B rows -> 16B-aligned frags)
constexpr int VPAD = 536;  // V^T row stride in shorts (1072B rows -> 16B-aligned)
}

typedef __bf16 bf16x8 __attribute__((ext_vector_type(8)));
typedef float  f32x16 __attribute__((ext_vector_type(16)));
typedef unsigned int uint32x4 __attribute__((ext_vector_type(4)));

// dst.lo = bf16(x), dst.hi = bf16(y) — single VALU op (RNE)
__device__ inline unsigned cvtpk(float x, float y) {
    unsigned r;
    asm("v_cvt_pk_bf16_f32 %0, %1, %2" : "=v"(r) : "v"(x), "v"(y));
    return r;
}

__global__ __launch_bounds__(512, 2) void attn_kernel(const float* __restrict__ qkv,
                                                      const float* __restrict__ cw,
                                                      const float* __restrict__ cb,
                                                      float* __restrict__ out) {
    const int blk = blockIdx.x;          // 0..255
    const int w   = blk >> 2;            // window 0..63
    const int h   = blk & 3;             // head
    const int b   = w >> 3;
    const int wb  = w & 7;
    const int tid = threadIdx.x;         // 0..511
    const int wv  = tid >> 6;            // wave 0..7 -> 64 q rows each (2 q-tiles)
    const int lane = tid & 63;
    const int l31 = lane & 31;
    const int h5  = lane >> 5;

    const float* qp = qkv;
    const float* kp = qkv + (size_t)Bn * LL * Cc;
    const float* vp = qkv + (size_t)2 * Bn * LL * Cc;

    __shared__ short K_lds[NTOK][KPAD];
    __shared__ short VT_lds[HD][VPAD];

    // ---- Q fragments: two q-tiles, qtok = wv*64 + qt*32 + l31 ----
    bf16x8 qf00, qf01, qf10, qf11;       // [qt][dc], named (no arrays)
    {
#pragma unroll
        for (int qt = 0; qt < 2; ++qt) {
            const int qtok = wv * 64 + qt * 32 + l31;
            const int qlqi = (qtok >> 3) * Ww + wb * WSP + (qtok & 7);
            const float* p = qp + ((size_t)b * LL + qlqi) * Cc + h * HD + h5 * 8;
#pragma unroll
            for (int dc = 0; dc < 2; ++dc) {
                float4 a = *reinterpret_cast<const float4*>(p + dc * 16);
                float4 c = *reinterpret_cast<const float4*>(p + dc * 16 + 4);
                uint32x4 u;
                u.x = cvtpk(a.x * SCALE_L2E, a.y * SCALE_L2E);
                u.y = cvtpk(a.z * SCALE_L2E, a.w * SCALE_L2E);
                u.z = cvtpk(c.x * SCALE_L2E, c.y * SCALE_L2E);
                u.w = cvtpk(c.z * SCALE_L2E, c.w * SCALE_L2E);
                const bf16x8 qv = __builtin_bit_cast(bf16x8, u);
                if (qt == 0 && dc == 0) qf00 = qv;
                if (qt == 0 && dc == 1) qf01 = qv;
                if (qt == 1 && dc == 0) qf10 = qv;
                if (qt == 1 && dc == 1) qf11 = qv;
            }
        }
    }

    // ---- stage K and V^T (bf16), token-pair scheme: 2048 items / 512 thr ----
    for (int i = tid; i < (NTOK / 2) * 8; i += 512) {
        const int tp = i >> 3, j = i & 7;      // token pair, d-group
        const int t0 = tp * 2, t1 = t0 + 1;
        const int lqi0 = (t0 >> 3) * Ww + wb * WSP + (t0 & 7);  // lqi1 = lqi0+1
        const size_t b0 = ((size_t)b * LL + lqi0) * Cc + h * HD + j * 4;
        const float4 k0 = *reinterpret_cast<const float4*>(kp + b0);
        const float4 k1 = *reinterpret_cast<const float4*>(kp + b0 + Cc);
        uint2 pk0, pk1;
        pk0.x = cvtpk(k0.x, k0.y);  pk0.y = cvtpk(k0.z, k0.w);
        pk1.x = cvtpk(k1.x, k1.y);  pk1.y = cvtpk(k1.z, k1.w);
        *reinterpret_cast<uint2*>(&K_lds[t0][j * 4]) = pk0;
        *reinterpret_cast<uint2*>(&K_lds[t1][j * 4]) = pk1;
        const float4 v0 = *reinterpret_cast<const float4*>(vp + b0);
        const float4 v1 = *reinterpret_cast<const float4*>(vp + b0 + Cc);
        *reinterpret_cast<unsigned*>(&VT_lds[j * 4 + 0][t0]) = cvtpk(v0.x, v1.x);
        *reinterpret_cast<unsigned*>(&VT_lds[j * 4 + 1][t0]) = cvtpk(v0.y, v1.y);
        *reinterpret_cast<unsigned*>(&VT_lds[j * 4 + 2][t0]) = cvtpk(v0.z, v1.z);
        *reinterpret_cast<unsigned*>(&VT_lds[j * 4 + 3][t0]) = cvtpk(v0.w, v1.w);
    }
    __syncthreads();   // the only barrier

    f32x16 acc0  = (f32x16)(0.f), acc1  = (f32x16)(0.f);
    f32x16 lacc0 = (f32x16)(0.f), lacc1 = (f32x16)(0.f);
    const f32x16 z16 = (f32x16)(0.f);

    uint32x4 onesu;
    onesu.x = 0x3F803F80u; onesu.y = 0x3F803F80u;
    onesu.z = 0x3F803F80u; onesu.w = 0x3F803F80u;
    const bf16x8 onesf = __builtin_bit_cast(bf16x8, onesu);

    auto load_kf = [&](int kt, bf16x8* kf) {
        const int krow = kt * 32 + l31;
#pragma unroll
        for (int dc = 0; dc < 2; ++dc)
            kf[dc] = __builtin_bit_cast(bf16x8,
                *reinterpret_cast<const uint32x4*>(&K_lds[krow][dc * 16 + h5 * 8]));
    };
    auto load_vu = [&](int kt, uint32x4* vu) {
#pragma unroll
        for (int kw = 0; kw < 2; ++kw) {
            const int kcol = kt * 32 + kw * 16 + h5 * 8;
            vu[kw] = *reinterpret_cast<const uint32x4*>(&VT_lds[l31][kcol]);
        }
    };
    auto softmax_pv = [&](const f32x16& s, const uint32x4* vu,
                          f32x16& accR, f32x16& laccR) {
        float pe[16];
#pragma unroll
        for (int i = 0; i < 16; ++i) pe[i] = __builtin_amdgcn_exp2f(s[i]);
        unsigned dw[8];
#pragma unroll
        for (int i = 0; i < 8; ++i) dw[i] = cvtpk(pe[2 * i], pe[2 * i + 1]);
#pragma unroll
        for (int kw = 0; kw < 2; ++kw) {
            unsigned a0 = dw[4 * kw + 0], b0 = dw[4 * kw + 2];
            unsigned a1 = dw[4 * kw + 1], b1 = dw[4 * kw + 3];
            asm("v_permlane32_swap_b32 %0, %1" : "+v"(a0), "+v"(b0));
            asm("v_permlane32_swap_b32 %0, %1" : "+v"(a1), "+v"(b1));
            uint32x4 pu; pu.x = a0; pu.y = a1; pu.z = b0; pu.w = b1;
            const bf16x8 pf = __builtin_bit_cast(bf16x8, pu);
            accR  = __builtin_amdgcn_mfma_f32_32x32x16_bf16(
                pf, __builtin_bit_cast(bf16x8, vu[kw]), accR, 0, 0, 0);
            laccR = __builtin_amdgcn_mfma_f32_32x32x16_bf16(
                pf, onesf, laccR, 0, 0, 0);
        }
    };

    bf16x8 kf[2];
    load_kf(0, kf);

    // ---- main loop: 16 tiles of 32 keys; one kf/vu read feeds BOTH q-tiles ----
    for (int kt = 0; kt < 16; ++kt) {
        f32x16 s0 = z16, s1 = z16;
        s0 = __builtin_amdgcn_mfma_f32_32x32x16_bf16(kf[0], qf00, s0, 0, 0, 0);
        s0 = __builtin_amdgcn_mfma_f32_32x32x16_bf16(kf[1], qf01, s0, 0, 0, 0);
        s1 = __builtin_amdgcn_mfma_f32_32x32x16_bf16(kf[0], qf10, s1, 0, 0, 0);
        s1 = __builtin_amdgcn_mfma_f32_32x32x16_bf16(kf[1], qf11, s1, 0, 0, 0);
        // lane holds S^T[k][q=l31] per qt, k = (reg&3)+8*(reg>>2)+4*h5+kt*32

        bf16x8 kfn[2];
        load_kf((kt + 1) & 15, kfn);
        uint32x4 vu[2];
        load_vu(kt, vu);

        softmax_pv(s0, vu, acc0, lacc0);   // qt1's s1 retires under qt0's exps
        softmax_pv(s1, vu, acc1, lacc1);

        kf[0] = kfn[0];
        kf[1] = kfn[1];
    }

    // ---- LePE conv + epilogue, per q-tile ----
    const int ch = h * HD + l31;
    float wreg[9];
#pragma unroll
    for (int wi = 0; wi < 9; ++wi) wreg[wi] = cw[ch * 9 + wi];
    const float bias = cb[ch];

    auto do_epi = [&](int tok0, const f32x16& accR, const f32x16& laccR) {
        // Packed V halo: 52 bf16 toks [tok0 + 4*h5 - 12, +40) as 26 uints.
        unsigned hw[26];
        const int segbase = tok0 + 4 * h5 - 12;
#pragma unroll
        for (int c2 = 0; c2 < 13; ++c2) {
            int t = segbase + 4 * c2;
            t = t < 0 ? 0 : (t > NTOK - 4 ? NTOK - 4 : t);
            const uint2 u = *reinterpret_cast<const uint2*>(&VT_lds[l31][t]);
            hw[c2 * 2 + 0] = u.x;
            hw[c2 * 2 + 1] = u.y;
        }
#pragma unroll
        for (int r = 0; r < 16; ++r) {
            const int c_r = (r & 3) + 8 * (r >> 2);           // compile-time
            const float iv = __builtin_amdgcn_rcpf(laccR[r]); // 1/lsum, in-lane
            const int tok = tok0 + c_r + 4 * h5;
            float cv = bias;
#pragma unroll
            for (int dy = -1; dy <= 1; ++dy) {
                const bool rowok = (unsigned)(tok + dy * 8) < (unsigned)NTOK;
#pragma unroll
                for (int dx = -1; dx <= 1; ++dx) {
                    const int idx = c_r + 12 + dy * 8 + dx;   // in [3,48]
                    const unsigned word = hw[idx >> 1];
                    const float tap = __builtin_bit_cast(float,
                        (idx & 1) ? (word & 0xFFFF0000u) : (word << 16));
                    bool ok = rowok;
                    if (dx == -1) ok = ok && (((r & 3) != 0) || (h5 != 0));  // wc > 0
                    if (dx == +1) ok = ok && (((r & 3) != 3) || (h5 == 0));  // wc < 7
                    cv += ok ? wreg[(dy + 1) * 3 + (dx + 1)] * tap : 0.f;
                }
            }
            const int lqi = (tok >> 3) * Ww + wb * WSP + (tok & 7);
            out[((size_t)b * LL + lqi) * Cc + ch] = accR[r] * iv + cv;
        }
    };

    do_epi(wv * 64, acc0, lacc0);
    do_epi(wv * 64 + 32, acc1, lacc1);
}

extern "C" void kernel_launch(void* const* d_in, const int* in_sizes, int n_in,
                              void* d_out, int out_size, void* d_ws, size_t ws_size,
                              hipStream_t stream) {
    const float* qkv = (const float*)d_in[0];
    const float* cw  = (const float*)d_in[1];
    const float* cb  = (const float*)d_in[2];
    float* out = (float*)d_out;

    attn_kernel<<<256, 512, 0, stream>>>(qkv, cw, cb, out);
}

// Round 23
// 28.748 us; speedup vs baseline: 1.4417x; 1.1177x over previous
//
#include <hip/hip_runtime.h>

// LePE window attention, 32x32x16 bf16 MFMA, reg-P via v_permlane32_swap_b32.
// R23 = R14 restored byte-identical (best known passing: 28.7 us).
// R22's vu-double-buffer variant failed correctness despite being
// value-equivalent (LDS immutable during loop) — suspected regalloc
// miscompile at ~96+ VGPR ext-vector pressure or container flake; not
// debuggable blind. Theory ledger closed (R11/R12/R13/R15/R16/R19-R22):
// every overlap/occupancy lever measured null, negative, or spilled.
// Structure: 256 blocks x 1024 threads (16 waves), K/V staged once per
// (window, head). LDS = K[512][40] + V^T[32][536] bf16 = 73.5 KB.

namespace {
constexpr int Bn   = 8;
constexpr int Ww   = 64;
constexpr int Cc   = 128;
constexpr int HD   = 32;
constexpr int WSP  = 8;
constexpr int NTOK = 512;
constexpr int LL   = 64 * 64;
// 32^-0.5 * log2(e): exp(s) == exp2(s') with scale folded into Q
constexpr float SCALE_L2E = 0.17677669529663687f * 1.4426950408889634f;
constexpr int KPAD = 40;   // K row stride in shorts (80B rows -> 16B-aligned frags)
constexpr int VPAD = 536;  // V^T row stride in shorts (1072B rows -> 16B-aligned)
}

typedef __bf16 bf16x8 __attribute__((ext_vector_type(8)));
typedef float  f32x16 __attribute__((ext_vector_type(16)));
typedef unsigned int uint32x4 __attribute__((ext_vector_type(4)));

// dst.lo = bf16(x), dst.hi = bf16(y) — single VALU op (RNE)
__device__ inline unsigned cvtpk(float x, float y) {
    unsigned r;
    asm("v_cvt_pk_bf16_f32 %0, %1, %2" : "=v"(r) : "v"(x), "v"(y));
    return r;
}

__global__ __launch_bounds__(1024, 4) void attn_kernel(const float* __restrict__ qkv,
                                                       const float* __restrict__ cw,
                                                       const float* __restrict__ cb,
                                                       float* __restrict__ out) {
    const int blk = blockIdx.x;          // 0..255
    const int w   = blk >> 2;            // window 0..63
    const int h   = blk & 3;             // head
    const int b   = w >> 3;
    const int wb  = w & 7;
    const int tid = threadIdx.x;         // 0..1023
    const int wv  = tid >> 6;            // wave 0..15 -> 32 q rows each
    const int lane = tid & 63;
    const int l31 = lane & 31;
    const int h5  = lane >> 5;

    const float* qp = qkv;
    const float* kp = qkv + (size_t)Bn * LL * Cc;
    const float* vp = qkv + (size_t)2 * Bn * LL * Cc;

    __shared__ short K_lds[NTOK][KPAD];
    __shared__ short VT_lds[HD][VPAD];

    // ---- staging: issue ALL global loads first (T14-lite) ----
    const int tpa = tid >> 3,          ja = tid & 7;
    const int tpb = (tid + 1024) >> 3, jb = (tid + 1024) & 7;
    const int t0a = tpa * 2, t0b = tpb * 2;
    const int lqa = (t0a >> 3) * Ww + wb * WSP + (t0a & 7);
    const int lqb = (t0b >> 3) * Ww + wb * WSP + (t0b & 7);
    const size_t ga = ((size_t)b * LL + lqa) * Cc + h * HD + ja * 4;
    const size_t gb = ((size_t)b * LL + lqb) * Cc + h * HD + jb * 4;
    const float4 k0a = *reinterpret_cast<const float4*>(kp + ga);
    const float4 k1a = *reinterpret_cast<const float4*>(kp + ga + Cc);
    const float4 v0a = *reinterpret_cast<const float4*>(vp + ga);
    const float4 v1a = *reinterpret_cast<const float4*>(vp + ga + Cc);
    const float4 k0b = *reinterpret_cast<const float4*>(kp + gb);
    const float4 k1b = *reinterpret_cast<const float4*>(kp + gb + Cc);
    const float4 v0b = *reinterpret_cast<const float4*>(vp + gb);
    const float4 v1b = *reinterpret_cast<const float4*>(vp + gb + Cc);

    const int qtok = wv * 32 + l31;      // q tok; d = dc*16 + h5*8 + e
    const int qlqi = (qtok >> 3) * Ww + wb * WSP + (qtok & 7);
    const float* qptr = qp + ((size_t)b * LL + qlqi) * Cc + h * HD + h5 * 8;
    const float4 qa0 = *reinterpret_cast<const float4*>(qptr);
    const float4 qc0 = *reinterpret_cast<const float4*>(qptr + 4);
    const float4 qa1 = *reinterpret_cast<const float4*>(qptr + 16);
    const float4 qc1 = *reinterpret_cast<const float4*>(qptr + 20);

    // ---- convert + LDS write ----
    {
        uint2 pk0, pk1;
        pk0.x = cvtpk(k0a.x, k0a.y);  pk0.y = cvtpk(k0a.z, k0a.w);
        pk1.x = cvtpk(k1a.x, k1a.y);  pk1.y = cvtpk(k1a.z, k1a.w);
        *reinterpret_cast<uint2*>(&K_lds[t0a][ja * 4]) = pk0;
        *reinterpret_cast<uint2*>(&K_lds[t0a + 1][ja * 4]) = pk1;
        *reinterpret_cast<unsigned*>(&VT_lds[ja * 4 + 0][t0a]) = cvtpk(v0a.x, v1a.x);
        *reinterpret_cast<unsigned*>(&VT_lds[ja * 4 + 1][t0a]) = cvtpk(v0a.y, v1a.y);
        *reinterpret_cast<unsigned*>(&VT_lds[ja * 4 + 2][t0a]) = cvtpk(v0a.z, v1a.z);
        *reinterpret_cast<unsigned*>(&VT_lds[ja * 4 + 3][t0a]) = cvtpk(v0a.w, v1a.w);
    }
    {
        uint2 pk0, pk1;
        pk0.x = cvtpk(k0b.x, k0b.y);  pk0.y = cvtpk(k0b.z, k0b.w);
        pk1.x = cvtpk(k1b.x, k1b.y);  pk1.y = cvtpk(k1b.z, k1b.w);
        *reinterpret_cast<uint2*>(&K_lds[t0b][jb * 4]) = pk0;
        *reinterpret_cast<uint2*>(&K_lds[t0b + 1][jb * 4]) = pk1;
        *reinterpret_cast<unsigned*>(&VT_lds[jb * 4 + 0][t0b]) = cvtpk(v0b.x, v1b.x);
        *reinterpret_cast<unsigned*>(&VT_lds[jb * 4 + 1][t0b]) = cvtpk(v0b.y, v1b.y);
        *reinterpret_cast<unsigned*>(&VT_lds[jb * 4 + 2][t0b]) = cvtpk(v0b.z, v1b.z);
        *reinterpret_cast<unsigned*>(&VT_lds[jb * 4 + 3][t0b]) = cvtpk(v0b.w, v1b.w);
    }

    // ---- Q fragments ----
    bf16x8 qf[2];
    {
        uint32x4 u;
        u.x = cvtpk(qa0.x * SCALE_L2E, qa0.y * SCALE_L2E);
        u.y = cvtpk(qa0.z * SCALE_L2E, qa0.w * SCALE_L2E);
        u.z = cvtpk(qc0.x * SCALE_L2E, qc0.y * SCALE_L2E);
        u.w = cvtpk(qc0.z * SCALE_L2E, qc0.w * SCALE_L2E);
        qf[0] = __builtin_bit_cast(bf16x8, u);
        u.x = cvtpk(qa1.x * SCALE_L2E, qa1.y * SCALE_L2E);
        u.y = cvtpk(qa1.z * SCALE_L2E, qa1.w * SCALE_L2E);
        u.z = cvtpk(qc1.x * SCALE_L2E, qc1.y * SCALE_L2E);
        u.w = cvtpk(qc1.z * SCALE_L2E, qc1.w * SCALE_L2E);
        qf[1] = __builtin_bit_cast(bf16x8, u);
    }
    __syncthreads();   // the only barrier

    f32x16 acc  = (f32x16)(0.f);
    f32x16 lacc = (f32x16)(0.f);         // row-sum accumulator (ones-MFMA)
    const f32x16 z16 = (f32x16)(0.f);

    // ones B-fragment: every element bf16 1.0
    uint32x4 onesu;
    onesu.x = 0x3F803F80u; onesu.y = 0x3F803F80u;
    onesu.z = 0x3F803F80u; onesu.w = 0x3F803F80u;
    const bf16x8 onesf = __builtin_bit_cast(bf16x8, onesu);

    auto load_kf = [&](int kt, bf16x8* kf) {
        const int krow = kt * 32 + l31;
#pragma unroll
        for (int dc = 0; dc < 2; ++dc)
            kf[dc] = __builtin_bit_cast(bf16x8,
                *reinterpret_cast<const uint32x4*>(&K_lds[krow][dc * 16 + h5 * 8]));
    };

    bf16x8 kf[2];
    load_kf(0, kf);

    // ---- main loop: 16 tiles of 32 keys, barrier-free ----
    for (int kt = 0; kt < 16; ++kt) {
        f32x16 s = z16;
        s = __builtin_amdgcn_mfma_f32_32x32x16_bf16(kf[0], qf[0], s, 0, 0, 0);
        s = __builtin_amdgcn_mfma_f32_32x32x16_bf16(kf[1], qf[1], s, 0, 0, 0);
        // lane holds S^T[k][q=l31], k = (reg&3) + 8*(reg>>2) + 4*h5 + kt*32

        // prefetch next kf + this kt's V fragments while s is in flight
        bf16x8 kfn[2];
        load_kf((kt + 1) & 15, kfn);
        uint32x4 vu[2];
#pragma unroll
        for (int kw = 0; kw < 2; ++kw) {
            const int kcol = kt * 32 + kw * 16 + h5 * 8;
            vu[kw] = *reinterpret_cast<const uint32x4*>(&VT_lds[l31][kcol]);
        }

        float pe[16];
#pragma unroll
        for (int i = 0; i < 16; ++i) pe[i] = __builtin_amdgcn_exp2f(s[i]);
        unsigned dw[8];
#pragma unroll
        for (int i = 0; i < 8; ++i) dw[i] = cvtpk(pe[2 * i], pe[2 * i + 1]);

        // PV + row-sum: per 16-key window kw, redistribute P across the h5
        // halves with 2x v_permlane32_swap_b32 (vdst_hi <-> vsrc_lo), then
        // one PV MFMA and one ones-MFMA (row sums, same r<->q map as acc).
#pragma unroll
        for (int kw = 0; kw < 2; ++kw) {
            unsigned a0 = dw[4 * kw + 0], b0 = dw[4 * kw + 2];
            unsigned a1 = dw[4 * kw + 1], b1 = dw[4 * kw + 3];
            asm("v_permlane32_swap_b32 %0, %1" : "+v"(a0), "+v"(b0));
            asm("v_permlane32_swap_b32 %0, %1" : "+v"(a1), "+v"(b1));
            uint32x4 pu; pu.x = a0; pu.y = a1; pu.z = b0; pu.w = b1;
            const bf16x8 pf = __builtin_bit_cast(bf16x8, pu);
            acc  = __builtin_amdgcn_mfma_f32_32x32x16_bf16(
                pf, __builtin_bit_cast(bf16x8, vu[kw]), acc, 0, 0, 0);
            lacc = __builtin_amdgcn_mfma_f32_32x32x16_bf16(
                pf, onesf, lacc, 0, 0, 0);
        }
        kf[0] = kfn[0];
        kf[1] = kfn[1];
    }

    // ---- LePE conv: lane owns channel d = l31 of head h ----
    const int ch = h * HD + l31;
    float wreg[9];
#pragma unroll
    for (int wi = 0; wi < 9; ++wi) wreg[wi] = cw[ch * 9 + wi];
    const float bias = cb[ch];

    const int tok0 = wv * 32;
    // Packed V halo: 52 bf16 toks [tok0 + 4*h5 - 12, +40) as 26 uints.
    // Needed tap range rel. tok0+4h5 is [-9,+36]; clamped chunk slots are only
    // tokens <0 / >=512, all rowok-guarded below.
    unsigned hw[26];
    {
        const int segbase = tok0 + 4 * h5 - 12;
#pragma unroll
        for (int c2 = 0; c2 < 13; ++c2) {
            int t = segbase + 4 * c2;
            t = t < 0 ? 0 : (t > NTOK - 4 ? NTOK - 4 : t);
            const uint2 u = *reinterpret_cast<const uint2*>(&VT_lds[l31][t]);
            hw[c2 * 2 + 0] = u.x;
            hw[c2 * 2 + 1] = u.y;
        }
    }

    // ---- epilogue: normalize (in-lane rcp of lacc) + conv + store ----
#pragma unroll
    for (int r = 0; r < 16; ++r) {
        const int c_r = (r & 3) + 8 * (r >> 2);           // q row offset (compile-time)
        const float iv = __builtin_amdgcn_rcpf(lacc[r]);  // 1/lsum for q_r, in-lane
        const int tok = tok0 + c_r + 4 * h5;
        float cv = bias;
#pragma unroll
        for (int dy = -1; dy <= 1; ++dy) {
            const bool rowok = (unsigned)(tok + dy * 8) < (unsigned)NTOK;
#pragma unroll
            for (int dx = -1; dx <= 1; ++dx) {
                const int idx = c_r + 12 + dy * 8 + dx;   // compile-time, in [3,48]
                const unsigned word = hw[idx >> 1];
                const float tap = __builtin_bit_cast(float,
                    (idx & 1) ? (word & 0xFFFF0000u) : (word << 16));
                bool ok = rowok;
                if (dx == -1) ok = ok && (((r & 3) != 0) || (h5 != 0));  // wc > 0
                if (dx == +1) ok = ok && (((r & 3) != 3) || (h5 == 0));  // wc < 7
                cv += ok ? wreg[(dy + 1) * 3 + (dx + 1)] * tap : 0.f;
            }
        }
        const int lqi = (tok >> 3) * Ww + wb * WSP + (tok & 7);
        out[((size_t)b * LL + lqi) * Cc + ch] = acc[r] * iv + cv;
    }
}

extern "C" void kernel_launch(void* const* d_in, const int* in_sizes, int n_in,
                              void* d_out, int out_size, void* d_ws, size_t ws_size,
                              hipStream_t stream) {
    const float* qkv = (const float*)d_in[0];
    const float* cw  = (const float*)d_in[1];
    const float* cb  = (const float*)d_in[2];
    float* out = (float*)d_out;

    attn_kernel<<<256, 1024, 0, stream>>>(qkv, cw, cb, out);
}